// Round 2
// baseline (8596.626 us; speedup 1.0000x reference)
//
#include <hip/hip_runtime.h>
#include <hip/hip_bf16.h>
#include <hip/hip_cooperative_groups.h>

namespace cg = cooperative_groups;

// ---------------------------------------------------------------------------
// Encoder: emb gather -> LSTM0 -> LSTM1 -> BatchNorm(inference)
// B=64, T=128, D=256, H=1024, 4H=4096, BT=8192 rows.
//
//  - Gate columns permuted: pc = j*4 + gate; weights stored transposed:
//    UbT[pc][k] bf16 so MFMA A/B fragments are contiguous 16B loads.
//  - Persistent cooperative recurrence kernel: 256 WGs (1/CU, LDS-forced),
//    U slice resident in LDS (128 KB, XOR-swizzled chunk^=(pc&7) so the
//    stride-2048B ds_read_b128 is bank-conflict-free), c in registers,
//    h exchanged via global bf16 ping-pong + grid.sync() per step.
// ---------------------------------------------------------------------------

typedef __attribute__((ext_vector_type(8))) short short8;
typedef __attribute__((ext_vector_type(4))) float f32x4;
typedef unsigned short ushort_t;

__device__ __forceinline__ ushort_t f2b(float f) {
  __hip_bfloat16 h = __float2bfloat16(f);
  return *reinterpret_cast<ushort_t*>(&h);
}
__device__ __forceinline__ float b2f(ushort_t u) {
  unsigned int x = ((unsigned int)u) << 16;
  return __builtin_bit_cast(float, x);
}
__device__ __forceinline__ float fsigmoid(float x) {
  return 1.f / (1.f + __expf(-x));
}
__device__ __forceinline__ float ftanh(float x) {
  // safe at +-inf: e=inf -> 1; e=0 -> -1
  return 1.f - 2.f / (__expf(2.f * x) + 1.f);
}

// ---- convert W/U [K][4096] f32 -> dst[pc][k] bf16 (transposed + permuted) --
__global__ __launch_bounds__(256) void k_convert_bt(
    const float* __restrict__ src, ushort_t* __restrict__ dst, int kshift) {
  int tid = blockIdx.x * 256 + threadIdx.x;       // tid = pc*K + k
  int K = 1 << kshift;
  int pc = tid >> kshift;
  int k = tid & (K - 1);
  int c = ((pc & 3) << 10) | (pc >> 2);           // original column
  dst[tid] = f2b(src[(size_t)k * 4096 + c]);
}

// ---- permute biases -------------------------------------------------------
__global__ __launch_bounds__(256) void k_bias(
    const float* __restrict__ b0, const float* __restrict__ b1,
    float* __restrict__ bp0, float* __restrict__ bp1) {
  int pc = blockIdx.x * 256 + threadIdx.x;
  int c = ((pc & 3) << 10) | (pc >> 2);
  bp0[pc] = b0[c];
  bp1[pc] = b1[c];
}

// ---- embedding gather: Xemb[(t*64+b)][d] = bf16(emb[tokens[b][t]][d]) -----
__global__ __launch_bounds__(256) void k_gather(
    const int* __restrict__ tokens, const float* __restrict__ emb,
    ushort_t* __restrict__ Xemb) {
  int row = blockIdx.x;            // row = t*64 + b
  int t = row >> 6, b = row & 63;
  int tok = tokens[b * 128 + t];
  int d = threadIdx.x;
  Xemb[(size_t)row * 256 + d] = f2b(emb[(size_t)tok * 256 + d]);
}

// ---- state init -----------------------------------------------------------
__global__ __launch_bounds__(256) void k_init(
    const float* __restrict__ h0, const float* __restrict__ c0,
    ushort_t* __restrict__ hbA, float* __restrict__ h_st,
    float* __restrict__ c_st) {
  int tid = blockIdx.x * 256 + threadIdx.x;
  hbA[tid] = f2b(h0[tid]);
  h_st[tid] = h0[tid];
  c_st[tid] = c0[tid];
}

// ---- bf16 GEMM: C[8192][4096] = A[8192][K] * BT[4096][K]^T ----------------
__global__ __launch_bounds__(256) void k_gemm_bt(
    const ushort_t* __restrict__ A, const ushort_t* __restrict__ BT,
    ushort_t* __restrict__ C, int K) {
  const int l = threadIdx.x & 63;
  const int wv = threadIdx.x >> 6;
  const int wvM = wv & 1, wvN = wv >> 1;
  const int wgM = blockIdx.x & 63;     // 8192/128
  const int wgN = blockIdx.x >> 6;     // 4096/128
  const int koff = (l >> 4) * 8;

  f32x4 acc[4][4] = {};
  const ushort_t* Ap = A + (size_t)(wgM * 128 + wvM * 64 + (l & 15)) * K + koff;
  const ushort_t* Bp = BT + (size_t)(wgN * 128 + wvN * 64 + (l & 15)) * K + koff;

  for (int k0 = 0; k0 < K; k0 += 32) {
    short8 a[4], b[4];
#pragma unroll
    for (int mt = 0; mt < 4; ++mt)
      a[mt] = *(const short8*)(Ap + (size_t)mt * 16 * K + k0);
#pragma unroll
    for (int nt = 0; nt < 4; ++nt)
      b[nt] = *(const short8*)(Bp + (size_t)nt * 16 * K + k0);
#pragma unroll
    for (int mt = 0; mt < 4; ++mt)
#pragma unroll
      for (int nt = 0; nt < 4; ++nt)
        acc[mt][nt] =
            __builtin_amdgcn_mfma_f32_16x16x32_bf16(a[mt], b[nt], acc[mt][nt], 0, 0, 0);
  }

  const int rr0 = wgM * 128 + wvM * 64 + (l >> 4) * 4;
  const int cc0 = wgN * 128 + wvN * 64 + (l & 15);
#pragma unroll
  for (int mt = 0; mt < 4; ++mt)
#pragma unroll
    for (int nt = 0; nt < 4; ++nt)
#pragma unroll
      for (int r = 0; r < 4; ++r)
        C[(size_t)(rr0 + mt * 16 + r) * 4096 + cc0 + nt * 16] =
            f2b(acc[mt][nt][r]);
}

// ---- persistent cooperative LSTM layer (128 steps) ------------------------
// 256 WGs = 4 M-blocks(16 rows) x 64 N-blocks(64 pc). 1 WG/CU (135 KB LDS).
__global__ __launch_bounds__(256, 1) void k_lstm_persist(
    const ushort_t* __restrict__ UbT,   // [4096][1024] bf16
    const ushort_t* __restrict__ XW,    // [8192][4096] bf16 (all t)
    const float* __restrict__ biasp,    // [4096] permuted
    ushort_t* __restrict__ hbA,         // bf16 h ping (t even: input)
    ushort_t* __restrict__ hbB,         // bf16 h pong
    float* __restrict__ c_st,           // [64][1024] f32 in (t=0) / out (t=127)
    float* __restrict__ h_st,           // [64][1024] f32 out (t=127)
    ushort_t* __restrict__ Hsave,       // layer0: H0all, else null
    float* __restrict__ norm_out,       // layer1: d_out, else null
    const float* __restrict__ gamma, const float* __restrict__ beta,
    const float* __restrict__ mean, const float* __restrict__ var) {
  cg::grid_group grid = cg::this_grid();

  const int l = threadIdx.x & 63;
  const int wv = threadIdx.x >> 6;
  const int wgM = blockIdx.x & 3;
  const int wgN = blockIdx.x >> 2;

  __shared__ ushort_t Ulds[64 * 1024];   // 128 KB, swizzled
  __shared__ float zbuf[4][16][17];      // +1 pad
  __shared__ float hbuf[16][17];         // epilogue transpose for coalesced writes

  // ---- stage U slice into LDS (chunk c stored at c ^ (row&7)) ----
  for (int i = threadIdx.x; i < 8192; i += 256) {
    int row = i >> 7;          // pc_local 0..63
    int ch = i & 127;          // 16B chunk within row
    short8 v = *(const short8*)(UbT + ((size_t)(wgN * 64 + row)) * 1024 + ch * 8);
    *(short8*)(Ulds + row * 1024 + (ch ^ (row & 7)) * 8) = v;
  }

  // ---- per-thread constants ----
  const int b_loc = l & 15, jl = l >> 4, lg = l >> 4;
  const int row = wgM * 16 + (l & 15);                // A row (batch)
  const int pc = wgN * 64 + wv * 16 + (l & 15);       // B col (permuted)
  const int pc_local = wv * 16 + (l & 15);
  const int bxor = pc_local & 7;
  const ushort_t* Bbase = Ulds + pc_local * 1024;
  const float bias_c = biasp[pc];

  const int bb = wgM * 16 + b_loc;                    // c-owner coords
  const int jj = wgN * 16 + wv * 4 + jl;
  const size_t cidx = (size_t)bb * 1024 + jj;
  float c_reg = c_st[cidx];

  // writer-role coords (coalesced epilogue)
  const int b2 = threadIdx.x >> 4, j2 = threadIdx.x & 15;
  const int bb2 = wgM * 16 + b2;
  const int jj2 = wgN * 16 + j2;
  float scl2 = 0.f, sft2 = 0.f;
  if (norm_out) {
    float inv = rsqrtf(var[jj2] + 1e-3f);
    scl2 = inv * gamma[jj2];
    sft2 = beta[jj2] - mean[jj2] * scl2;
  }

  __syncthreads();

  for (int t = 0; t < 128; ++t) {
    const ushort_t* hin = (t & 1) ? hbB : hbA;
    ushort_t* hout = (t & 1) ? hbA : hbB;
    const ushort_t* XWt = XW + (size_t)t * 64 * 4096;

    // preload A fragments (16 rows x K=1024 per wave; L1-resident across waves)
    const ushort_t* Ap = hin + (size_t)row * 1024 + lg * 8;
    short8 a[32];
#pragma unroll
    for (int k0 = 0; k0 < 32; ++k0) a[k0] = *(const short8*)(Ap + k0 * 32);

    // prefetch XW for epilogue
    const int drow = lg * 4;
    ushort_t xw[4];
#pragma unroll
    for (int r = 0; r < 4; ++r)
      xw[r] = XWt[(size_t)(wgM * 16 + drow + r) * 4096 + pc];

    // MFMA over K=1024, 4 independent chains
    f32x4 acc0 = {}, acc1 = {}, acc2 = {}, acc3 = {};
#pragma unroll
    for (int k0 = 0; k0 < 32; k0 += 4) {
      short8 q0 = *(const short8*)(Bbase + (((k0 + 0) * 4 + lg) ^ bxor) * 8);
      acc0 = __builtin_amdgcn_mfma_f32_16x16x32_bf16(a[k0 + 0], q0, acc0, 0, 0, 0);
      short8 q1 = *(const short8*)(Bbase + (((k0 + 1) * 4 + lg) ^ bxor) * 8);
      acc1 = __builtin_amdgcn_mfma_f32_16x16x32_bf16(a[k0 + 1], q1, acc1, 0, 0, 0);
      short8 q2 = *(const short8*)(Bbase + (((k0 + 2) * 4 + lg) ^ bxor) * 8);
      acc2 = __builtin_amdgcn_mfma_f32_16x16x32_bf16(a[k0 + 2], q2, acc2, 0, 0, 0);
      short8 q3 = *(const short8*)(Bbase + (((k0 + 3) * 4 + lg) ^ bxor) * 8);
      acc3 = __builtin_amdgcn_mfma_f32_16x16x32_bf16(a[k0 + 3], q3, acc3, 0, 0, 0);
    }

#pragma unroll
    for (int r = 0; r < 4; ++r) {
      float z = acc0[r] + acc1[r] + acc2[r] + acc3[r] + b2f(xw[r]) + bias_c;
      zbuf[wv][drow + r][l & 15] = z;
    }
    __syncthreads();

    // gate combine (c-owner role)
    float zi = zbuf[wv][b_loc][jl * 4 + 0];
    float zf = zbuf[wv][b_loc][jl * 4 + 1];
    float zg = zbuf[wv][b_loc][jl * 4 + 2];
    float zo = zbuf[wv][b_loc][jl * 4 + 3];
    float ii = fsigmoid(zi), ff = fsigmoid(zf), oo = fsigmoid(zo);
    float gg = ftanh(zg);
    c_reg = ff * c_reg + ii * gg;
    float hn = oo * ftanh(c_reg);

    hbuf[b_loc][wv * 4 + jl] = hn;
    if (t == 127) c_st[cidx] = c_reg;
    __syncthreads();

    // coalesced writes (writer role)
    float hv = hbuf[b2][j2];
    ushort_t hb16 = f2b(hv);
    hout[(size_t)bb2 * 1024 + jj2] = hb16;
    if (Hsave) Hsave[(size_t)t * 65536 + (size_t)bb2 * 1024 + jj2] = hb16;
    if (norm_out)
      norm_out[((size_t)bb2 * 128 + t) * 1024 + jj2] = hv * scl2 + sft2;
    if (t == 127) h_st[(size_t)bb2 * 1024 + jj2] = hv;

    grid.sync();
  }
}

// ---- one LSTM timestep (fallback path if coop launch unavailable) ---------
__global__ __launch_bounds__(256) void k_lstm_step(
    const ushort_t* __restrict__ hb, const ushort_t* __restrict__ UbT,
    const ushort_t* __restrict__ XWt, const float* __restrict__ biasp,
    float* __restrict__ c_st, float* __restrict__ h_st,
    ushort_t* __restrict__ hb_out, ushort_t* __restrict__ Hsave,
    float* __restrict__ norm_out, const float* __restrict__ gamma,
    const float* __restrict__ beta, const float* __restrict__ mean,
    const float* __restrict__ var, int t) {
  const int l = threadIdx.x & 63;
  const int wv = threadIdx.x >> 6;
  const int wgM = blockIdx.x & 3;
  const int wgN = blockIdx.x >> 2;
  const int row = wgM * 16 + (l & 15);
  const int pc = wgN * 64 + wv * 16 + (l & 15);
  const int koff = (l >> 4) * 8;

  f32x4 acc = {0.f, 0.f, 0.f, 0.f};
  const ushort_t* Ap = hb + (size_t)row * 1024 + koff;
  const ushort_t* Bp = UbT + (size_t)pc * 1024 + koff;
#pragma unroll 8
  for (int k0 = 0; k0 < 1024; k0 += 32) {
    short8 a = *(const short8*)(Ap + k0);
    short8 b = *(const short8*)(Bp + k0);
    acc = __builtin_amdgcn_mfma_f32_16x16x32_bf16(a, b, acc, 0, 0, 0);
  }

  __shared__ float zbuf[4][16][17];
  const int drow = (l >> 4) * 4;
#pragma unroll
  for (int r = 0; r < 4; ++r) {
    int rb = wgM * 16 + drow + r;
    float z = acc[r] + b2f(XWt[(size_t)rb * 4096 + pc]) + biasp[pc];
    zbuf[wv][drow + r][l & 15] = z;
  }
  __syncthreads();

  const int b_loc = l & 15, jl = l >> 4;
  float zi = zbuf[wv][b_loc][jl * 4 + 0];
  float zf = zbuf[wv][b_loc][jl * 4 + 1];
  float zg = zbuf[wv][b_loc][jl * 4 + 2];
  float zo = zbuf[wv][b_loc][jl * 4 + 3];
  const int b = wgM * 16 + b_loc;
  const int j = wgN * 16 + wv * 4 + jl;
  const size_t idx = (size_t)b * 1024 + j;

  float co = c_st[idx];
  float ii = fsigmoid(zi), ff = fsigmoid(zf), oo = fsigmoid(zo);
  float gg = ftanh(zg);
  float cn = ff * co + ii * gg;
  float hn = oo * ftanh(cn);

  c_st[idx] = cn;
  h_st[idx] = hn;
  hb_out[idx] = f2b(hn);
  if (Hsave) Hsave[idx] = f2b(hn);
  if (norm_out) {
    float nm = (hn - mean[j]) * rsqrtf(var[j] + 1e-3f) * gamma[j] + beta[j];
    norm_out[((size_t)b * 128 + t) * 1024 + j] = nm;
  }
}

// ---- final h,c copy -------------------------------------------------------
__global__ __launch_bounds__(256) void k_final(
    const float* __restrict__ h_st, const float* __restrict__ c_st,
    float* __restrict__ out) {
  int tid = blockIdx.x * 256 + threadIdx.x;
  out[8388608 + tid] = h_st[tid];
  out[8454144 + tid] = c_st[tid];
}

extern "C" void kernel_launch(void* const* d_in, const int* in_sizes, int n_in,
                              void* d_out, int out_size, void* d_ws,
                              size_t ws_size, hipStream_t stream) {
  const int* tokens = (const int*)d_in[0];
  const float* h0 = (const float*)d_in[1];
  const float* c0 = (const float*)d_in[2];
  const float* emb = (const float*)d_in[3];
  const float* W0 = (const float*)d_in[4];
  const float* U0 = (const float*)d_in[5];
  const float* b0 = (const float*)d_in[6];
  const float* W1 = (const float*)d_in[7];
  const float* U1 = (const float*)d_in[8];
  const float* b1 = (const float*)d_in[9];
  const float* gammap = (const float*)d_in[10];
  const float* betap = (const float*)d_in[11];
  const float* mmean = (const float*)d_in[12];
  const float* mvar = (const float*)d_in[13];

  char* ws = (char*)d_ws;
  ushort_t* UbT0 = (ushort_t*)(ws + 0);            //  8 MB [4096][1024]
  ushort_t* UbT1 = (ushort_t*)(ws + 8388608);      //  8 MB
  ushort_t* WbT0 = (ushort_t*)(ws + 16777216);     //  2 MB [4096][256]
  ushort_t* WbT1 = (ushort_t*)(ws + 18874368);     //  8 MB [4096][1024]
  float* bp0 = (float*)(ws + 27262976);            // 16 KB
  float* bp1 = (float*)(ws + 27279360);            // 16 KB
  ushort_t* Xemb = (ushort_t*)(ws + 27295744);     //  4 MB [8192][256]
  ushort_t* XW = (ushort_t*)(ws + 31490048);       // 64 MB [8192][4096]
  ushort_t* H0all = (ushort_t*)(ws + 98598912);    // 16 MB [8192][1024]
  ushort_t* hbA = (ushort_t*)(ws + 115376128);     // 128 KB
  ushort_t* hbB = (ushort_t*)(ws + 115507200);     // 128 KB
  float* h_st = (float*)(ws + 115638272);          // 256 KB
  float* c_st = (float*)(ws + 115900416);          // 256 KB

  k_convert_bt<<<16384, 256, 0, stream>>>(U0, UbT0, 10);
  k_convert_bt<<<16384, 256, 0, stream>>>(U1, UbT1, 10);
  k_convert_bt<<<4096, 256, 0, stream>>>(W0, WbT0, 8);
  k_convert_bt<<<16384, 256, 0, stream>>>(W1, WbT1, 10);
  k_bias<<<16, 256, 0, stream>>>(b0, b1, bp0, bp1);
  k_gather<<<8192, 256, 0, stream>>>(tokens, emb, Xemb);
  k_init<<<256, 256, 0, stream>>>(h0, c0, hbA, h_st, c_st);

  float* outp = (float*)d_out;

  // ---- layer 0 ----
  k_gemm_bt<<<2048, 256, 0, stream>>>(Xemb, WbT0, XW, 256);
  {
    const ushort_t* UbTp = UbT0;
    const ushort_t* XWp = XW;
    const float* bpp = bp0;
    ushort_t* hbAp = hbA;
    ushort_t* hbBp = hbB;
    float* cp = c_st;
    float* hp = h_st;
    ushort_t* Hsavep = H0all;
    float* normp = nullptr;
    const float* g = nullptr; const float* be = nullptr;
    const float* mn = nullptr; const float* vr = nullptr;
    void* args[] = {&UbTp, &XWp, &bpp, &hbAp, &hbBp, &cp, &hp,
                    &Hsavep, &normp, &g, &be, &mn, &vr};
    hipError_t e = hipLaunchCooperativeKernel((const void*)k_lstm_persist,
                                              dim3(256), dim3(256), args, 0, stream);
    if (e != hipSuccess) {
      (void)hipGetLastError();
      for (int t = 0; t < 128; ++t) {
        const ushort_t* hin = (t & 1) ? hbB : hbA;
        ushort_t* hout = (t & 1) ? hbA : hbB;
        k_lstm_step<<<256, 256, 0, stream>>>(
            hin, UbT0, XW + (size_t)t * 64 * 4096, bp0, c_st, h_st, hout,
            H0all + (size_t)t * 64 * 1024, nullptr, nullptr, nullptr, nullptr,
            nullptr, t);
      }
    }
  }

  // ---- layer 1 ----
  k_gemm_bt<<<2048, 256, 0, stream>>>(H0all, WbT1, XW, 1024);
  {
    const ushort_t* UbTp = UbT1;
    const ushort_t* XWp = XW;
    const float* bpp = bp1;
    ushort_t* hbAp = hbA;
    ushort_t* hbBp = hbB;
    float* cp = c_st;
    float* hp = h_st;
    ushort_t* Hsavep = nullptr;
    float* normp = outp;
    const float* g = gammap; const float* be = betap;
    const float* mn = mmean; const float* vr = mvar;
    void* args[] = {&UbTp, &XWp, &bpp, &hbAp, &hbBp, &cp, &hp,
                    &Hsavep, &normp, &g, &be, &mn, &vr};
    hipError_t e = hipLaunchCooperativeKernel((const void*)k_lstm_persist,
                                              dim3(256), dim3(256), args, 0, stream);
    if (e != hipSuccess) {
      (void)hipGetLastError();
      for (int t = 0; t < 128; ++t) {
        const ushort_t* hin = (t & 1) ? hbB : hbA;
        ushort_t* hout = (t & 1) ? hbA : hbB;
        k_lstm_step<<<256, 256, 0, stream>>>(
            hin, UbT1, XW + (size_t)t * 64 * 4096, bp1, c_st, h_st, hout,
            nullptr, outp, gammap, betap, mmean, mvar, t);
      }
    }
  }

  k_final<<<256, 256, 0, stream>>>(h_st, c_st, outp);
}

// Round 3
// 2759.995 us; speedup vs baseline: 3.1147x; 3.1147x over previous
//
#include <hip/hip_runtime.h>
#include <hip/hip_bf16.h>

// ---------------------------------------------------------------------------
// Encoder: emb gather -> LSTM0 -> LSTM1 -> BatchNorm(inference)
// B=64, T=128, D=256, H=1024, 4H=4096, BT=8192 rows.
//
//  - Gate columns permuted: pc = j*4 + gate; weights transposed: UbT[pc][k]
//    bf16 so MFMA A/B fragments are contiguous 16B loads.
//  - Recurrence: one kernel launch per timestep (kernel boundary = barrier;
//    measured: cg::grid.sync() costs ~30us/step on this HW -> abandoned).
//    Step kernel: 512 thr (8 waves, 2/SIMD), K split 2x across waves,
//    4 independent MFMA chains, XCD swizzle keeps each XCD's U slice (1 MB)
//    L2-resident across steps.
//  - Batched GEMMs: m97-style global_load_lds staged 128x128 tile, k-major
//    chunk LDS layout (conflict-free ds_read_b128), chunked XCD swizzle.
// ---------------------------------------------------------------------------

typedef __attribute__((ext_vector_type(8))) short short8;
typedef __attribute__((ext_vector_type(4))) short short4v;
typedef __attribute__((ext_vector_type(4))) float f32x4;
typedef unsigned short ushort_t;

__device__ __forceinline__ ushort_t f2b(float f) {
  __hip_bfloat16 h = __float2bfloat16(f);
  return *reinterpret_cast<ushort_t*>(&h);
}
__device__ __forceinline__ float b2f(ushort_t u) {
  unsigned int x = ((unsigned int)u) << 16;
  return __builtin_bit_cast(float, x);
}
__device__ __forceinline__ float fsigmoid(float x) {
  return 1.f / (1.f + __expf(-x));
}
__device__ __forceinline__ float ftanh(float x) {
  return 1.f - 2.f / (__expf(2.f * x) + 1.f);
}

__device__ __forceinline__ void gload_lds16(const ushort_t* g, ushort_t* l) {
  __builtin_amdgcn_global_load_lds(
      (const __attribute__((address_space(1))) unsigned int*)g,
      (__attribute__((address_space(3))) unsigned int*)l, 16, 0, 0);
}

// ---- convert W/U [K][4096] f32 -> dst[pc][k] bf16 (coalesced read) --------
__global__ __launch_bounds__(256) void k_convert(
    const float* __restrict__ src, ushort_t* __restrict__ dst, int kshift) {
  size_t tid = (size_t)blockIdx.x * 256 + threadIdx.x;  // = k*4096 + c
  int k = (int)(tid >> 12);
  int c = (int)(tid & 4095);
  int pc = ((c & 1023) << 2) | (c >> 10);
  dst[((size_t)pc << kshift) + k] = f2b(src[tid]);
}

// ---- permute biases -------------------------------------------------------
__global__ __launch_bounds__(256) void k_bias(
    const float* __restrict__ b0, const float* __restrict__ b1,
    float* __restrict__ bp0, float* __restrict__ bp1) {
  int pc = blockIdx.x * 256 + threadIdx.x;
  int c = ((pc & 3) << 10) | (pc >> 2);
  bp0[pc] = b0[c];
  bp1[pc] = b1[c];
}

// ---- embedding gather -----------------------------------------------------
__global__ __launch_bounds__(256) void k_gather(
    const int* __restrict__ tokens, const float* __restrict__ emb,
    ushort_t* __restrict__ Xemb) {
  int row = blockIdx.x;            // row = t*64 + b
  int t = row >> 6, b = row & 63;
  int tok = tokens[b * 128 + t];
  int d = threadIdx.x;
  Xemb[(size_t)row * 256 + d] = f2b(emb[(size_t)tok * 256 + d]);
}

// ---- state init -----------------------------------------------------------
__global__ __launch_bounds__(256) void k_init(
    const float* __restrict__ h0, const float* __restrict__ c0,
    ushort_t* __restrict__ hbA, float* __restrict__ h_st,
    float* __restrict__ c_st) {
  int tid = blockIdx.x * 256 + threadIdx.x;
  hbA[tid] = f2b(h0[tid]);
  h_st[tid] = h0[tid];
  c_st[tid] = c0[tid];
}

// ---- m97-style GEMM: C[8192][4096] = A[8192][K] * BT[4096][K]^T -----------
// 128x128 tile, 4 waves 2x2, global_load_lds staging, k-major chunk layout:
// LDS chunk (kc*128 + r) holds X[row r][k0 + kc*8 .. +7]  (16B).
__global__ __launch_bounds__(256) void k_gemm_lds(
    const ushort_t* __restrict__ A, const ushort_t* __restrict__ BT,
    ushort_t* __restrict__ C, int K, int nwg) {
  const int cpx = nwg >> 3;                       // chunked XCD swizzle
  const int wgid = (blockIdx.x & 7) * cpx + (blockIdx.x >> 3);
  const int wgM = wgid & 63;                      // M=8192/128
  const int wgN = wgid >> 6;
  const int tid = threadIdx.x;
  const int l = tid & 63;
  const int wv = tid >> 6;
  const int wvM = wv & 1, wvN = wv >> 1;

  __shared__ __align__(16) ushort_t Alds[4096];   // 8 KB
  __shared__ __align__(16) ushort_t Blds[4096];   // 8 KB

  const int m0 = wgM * 128, n0 = wgN * 128;
  f32x4 acc[4][4] = {};

  for (int k0 = 0; k0 < K; k0 += 32) {
    __syncthreads();
#pragma unroll
    for (int j = 0; j < 2; ++j) {
      int c = j * 256 + tid;
      int kc = c >> 7, r = c & 127;
      ushort_t* lbase = (ushort_t*)&Alds[(size_t)(j * 256 + (tid & ~63)) * 8];
      gload_lds16(A + (size_t)(m0 + r) * K + k0 + kc * 8, lbase);
      ushort_t* lbaseB = (ushort_t*)&Blds[(size_t)(j * 256 + (tid & ~63)) * 8];
      gload_lds16(BT + (size_t)(n0 + r) * K + k0 + kc * 8, lbaseB);
    }
    __syncthreads();

    short8 af[4], bf[4];
#pragma unroll
    for (int mt = 0; mt < 4; ++mt)
      af[mt] = *(const short8*)&Alds[((l >> 4) * 128 + wvM * 64 + mt * 16 + (l & 15)) * 8];
#pragma unroll
    for (int nt = 0; nt < 4; ++nt)
      bf[nt] = *(const short8*)&Blds[((l >> 4) * 128 + wvN * 64 + nt * 16 + (l & 15)) * 8];
#pragma unroll
    for (int mt = 0; mt < 4; ++mt)
#pragma unroll
      for (int nt = 0; nt < 4; ++nt)
        acc[mt][nt] =
            __builtin_amdgcn_mfma_f32_16x16x32_bf16(af[mt], bf[nt], acc[mt][nt], 0, 0, 0);
  }

  const int rr0 = wgM * 128 + wvM * 64 + (l >> 4) * 4;
  const int cc0 = wgN * 128 + wvN * 64 + (l & 15);
#pragma unroll
  for (int mt = 0; mt < 4; ++mt)
#pragma unroll
    for (int nt = 0; nt < 4; ++nt)
#pragma unroll
      for (int r = 0; r < 4; ++r)
        C[(size_t)(rr0 + mt * 16 + r) * 4096 + cc0 + nt * 16] =
            f2b(acc[mt][nt][r]);
}

// ---- one LSTM timestep ----------------------------------------------------
// 256 WGs (XCD-swizzled) x 512 thr. WG tile: [16 rows x 64 pc], K=1024
// split in 2 halves across waves: wave wv -> n-tile (wv&3), k-half (wv>>2).
// 4 independent MFMA chains per wave; partial sums combined via LDS.
__global__ __launch_bounds__(512, 2) void k_lstm_step(
    const ushort_t* __restrict__ hb,    // [64][1024] bf16 (step input)
    const ushort_t* __restrict__ UbT,   // [4096][1024] bf16
    const ushort_t* __restrict__ XWt,   // [64][4096] bf16 (this t)
    const float* __restrict__ biasp,    // [4096] permuted
    float* __restrict__ c_st,           // [64][1024] f32 in/out
    float* __restrict__ h_st,           // [64][1024] f32 out (t=127)
    ushort_t* __restrict__ hb_out,      // [64][1024] bf16 out
    ushort_t* __restrict__ Hsave,       // layer0: H0all + t*65536, else null
    float* __restrict__ norm_out,       // layer1: d_out, else null
    const float* __restrict__ gamma, const float* __restrict__ beta,
    const float* __restrict__ mean, const float* __restrict__ var, int t) {
  const int tid = threadIdx.x;
  const int l = tid & 63;
  const int wv = tid >> 6;              // 0..7
  const int n = wv & 3;                 // n-tile (16 pc)
  const int kh = wv >> 2;               // k-half
  // XCD swizzle: blockIdx%8 selects XCD; make wgN>>3 == blockIdx%8 so each
  // XCD touches only 8 wgN slices (1 MB of U -> L2-resident across steps).
  const int bid = blockIdx.x;
  const int wgN = ((bid >> 3) & 7) | ((bid & 7) << 3);
  const int wgM = bid >> 6;

  const int row = wgM * 16 + (l & 15);
  const int pc = wgN * 64 + n * 16 + (l & 15);
  const int kbase = kh * 512 + (l >> 4) * 8;

  const ushort_t* Ap = hb + (size_t)row * 1024 + kbase;
  const ushort_t* Bp = UbT + (size_t)pc * 1024 + kbase;

  f32x4 acc0 = {}, acc1 = {}, acc2 = {}, acc3 = {};
#pragma unroll
  for (int k0 = 0; k0 < 16; k0 += 4) {
    short8 a0 = *(const short8*)(Ap + (k0 + 0) * 32);
    short8 b0 = *(const short8*)(Bp + (k0 + 0) * 32);
    short8 a1 = *(const short8*)(Ap + (k0 + 1) * 32);
    short8 b1 = *(const short8*)(Bp + (k0 + 1) * 32);
    short8 a2 = *(const short8*)(Ap + (k0 + 2) * 32);
    short8 b2 = *(const short8*)(Bp + (k0 + 2) * 32);
    short8 a3 = *(const short8*)(Ap + (k0 + 3) * 32);
    short8 b3 = *(const short8*)(Bp + (k0 + 3) * 32);
    acc0 = __builtin_amdgcn_mfma_f32_16x16x32_bf16(a0, b0, acc0, 0, 0, 0);
    acc1 = __builtin_amdgcn_mfma_f32_16x16x32_bf16(a1, b1, acc1, 0, 0, 0);
    acc2 = __builtin_amdgcn_mfma_f32_16x16x32_bf16(a2, b2, acc2, 0, 0, 0);
    acc3 = __builtin_amdgcn_mfma_f32_16x16x32_bf16(a3, b3, acc3, 0, 0, 0);
  }

  __shared__ float zbuf[2][4][16][17];
  {
    const int drow = (l >> 4) * 4;
#pragma unroll
    for (int r = 0; r < 4; ++r)
      zbuf[kh][n][drow + r][l & 15] = acc0[r] + acc1[r] + acc2[r] + acc3[r];
  }
  __syncthreads();

  if (tid < 256) {
    const int b_loc = tid >> 4, j_loc = tid & 15;
    const int ne = j_loc >> 2;
    const int cbase = (j_loc & 3) * 4;
    const int rowg = wgM * 16 + b_loc;
    const int jcol = wgN * 16 + j_loc;
    const int pcb = wgN * 64 + j_loc * 4;

    short4v xw = *(const short4v*)(XWt + (size_t)rowg * 4096 + pcb);
    f32x4 bia = *(const f32x4*)(biasp + pcb);

    float zi = zbuf[0][ne][b_loc][cbase + 0] + zbuf[1][ne][b_loc][cbase + 0] +
               b2f((ushort_t)xw[0]) + bia[0];
    float zf = zbuf[0][ne][b_loc][cbase + 1] + zbuf[1][ne][b_loc][cbase + 1] +
               b2f((ushort_t)xw[1]) + bia[1];
    float zg = zbuf[0][ne][b_loc][cbase + 2] + zbuf[1][ne][b_loc][cbase + 2] +
               b2f((ushort_t)xw[2]) + bia[2];
    float zo = zbuf[0][ne][b_loc][cbase + 3] + zbuf[1][ne][b_loc][cbase + 3] +
               b2f((ushort_t)xw[3]) + bia[3];

    const size_t idx = (size_t)rowg * 1024 + jcol;
    float co = c_st[idx];
    float ii = fsigmoid(zi), ff = fsigmoid(zf), oo = fsigmoid(zo);
    float gg = ftanh(zg);
    float cn = ff * co + ii * gg;
    float hn = oo * ftanh(cn);

    c_st[idx] = cn;
    ushort_t hb16 = f2b(hn);
    hb_out[idx] = hb16;
    if (Hsave) Hsave[idx] = hb16;
    if (norm_out) {
      float inv = rsqrtf(var[jcol] + 1e-3f);
      float scl = inv * gamma[jcol];
      float sft = beta[jcol] - mean[jcol] * scl;
      norm_out[((size_t)rowg * 128 + t) * 1024 + jcol] = hn * scl + sft;
    }
    if (t == 127) h_st[idx] = hn;
  }
}

// ---- final h,c copy -------------------------------------------------------
__global__ __launch_bounds__(256) void k_final(
    const float* __restrict__ h_st, const float* __restrict__ c_st,
    float* __restrict__ out) {
  int tid = blockIdx.x * 256 + threadIdx.x;
  out[8388608 + tid] = h_st[tid];
  out[8454144 + tid] = c_st[tid];
}

extern "C" void kernel_launch(void* const* d_in, const int* in_sizes, int n_in,
                              void* d_out, int out_size, void* d_ws,
                              size_t ws_size, hipStream_t stream) {
  const int* tokens = (const int*)d_in[0];
  const float* h0 = (const float*)d_in[1];
  const float* c0 = (const float*)d_in[2];
  const float* emb = (const float*)d_in[3];
  const float* W0 = (const float*)d_in[4];
  const float* U0 = (const float*)d_in[5];
  const float* b0 = (const float*)d_in[6];
  const float* W1 = (const float*)d_in[7];
  const float* U1 = (const float*)d_in[8];
  const float* b1 = (const float*)d_in[9];
  const float* gammap = (const float*)d_in[10];
  const float* betap = (const float*)d_in[11];
  const float* mmean = (const float*)d_in[12];
  const float* mvar = (const float*)d_in[13];

  char* ws = (char*)d_ws;
  ushort_t* UbT0 = (ushort_t*)(ws + 0);            //  8 MB [4096][1024]
  ushort_t* UbT1 = (ushort_t*)(ws + 8388608);      //  8 MB
  ushort_t* WbT0 = (ushort_t*)(ws + 16777216);     //  2 MB [4096][256]
  ushort_t* WbT1 = (ushort_t*)(ws + 18874368);     //  8 MB [4096][1024]
  float* bp0 = (float*)(ws + 27262976);            // 16 KB
  float* bp1 = (float*)(ws + 27279360);            // 16 KB
  ushort_t* Xemb = (ushort_t*)(ws + 27295744);     //  4 MB [8192][256]
  ushort_t* XW = (ushort_t*)(ws + 31490048);       // 64 MB [8192][4096]
  ushort_t* H0all = (ushort_t*)(ws + 98598912);    // 16 MB [8192][1024]
  ushort_t* hbA = (ushort_t*)(ws + 115376128);     // 128 KB
  ushort_t* hbB = (ushort_t*)(ws + 115507200);     // 128 KB
  float* h_st = (float*)(ws + 115638272);          // 256 KB
  float* c_st = (float*)(ws + 115900416);          // 256 KB

  k_convert<<<16384, 256, 0, stream>>>(U0, UbT0, 10);
  k_convert<<<16384, 256, 0, stream>>>(U1, UbT1, 10);
  k_convert<<<4096, 256, 0, stream>>>(W0, WbT0, 8);
  k_convert<<<16384, 256, 0, stream>>>(W1, WbT1, 10);
  k_bias<<<16, 256, 0, stream>>>(b0, b1, bp0, bp1);
  k_gather<<<8192, 256, 0, stream>>>(tokens, emb, Xemb);
  k_init<<<256, 256, 0, stream>>>(h0, c0, hbA, h_st, c_st);

  float* outp = (float*)d_out;

  // ---- layer 0 ----
  k_gemm_lds<<<2048, 256, 0, stream>>>(Xemb, WbT0, XW, 256, 2048);
  for (int t = 0; t < 128; ++t) {
    const ushort_t* hin = (t & 1) ? hbB : hbA;
    ushort_t* hout = (t & 1) ? hbA : hbB;
    k_lstm_step<<<256, 512, 0, stream>>>(
        hin, UbT0, XW + (size_t)t * 64 * 4096, bp0, c_st, h_st, hout,
        H0all + (size_t)t * 64 * 1024, nullptr, nullptr, nullptr, nullptr,
        nullptr, t);
  }

  // ---- layer 1 ----
  k_gemm_lds<<<2048, 256, 0, stream>>>(H0all, WbT1, XW, 1024, 2048);
  for (int t = 0; t < 128; ++t) {
    const ushort_t* hin = (t & 1) ? hbB : hbA;
    ushort_t* hout = (t & 1) ? hbA : hbB;
    k_lstm_step<<<256, 512, 0, stream>>>(
        hin, UbT1, XW + (size_t)t * 64 * 4096, bp1, c_st, h_st, hout, nullptr,
        outp, gammap, betap, mmean, mvar, t);
  }

  k_final<<<256, 256, 0, stream>>>(h_st, c_st, outp);
}

// Round 4
// 1682.657 us; speedup vs baseline: 5.1090x; 1.6403x over previous
//
#include <hip/hip_runtime.h>
#include <hip/hip_bf16.h>

// ---------------------------------------------------------------------------
// Encoder: emb gather -> LSTM0 -> LSTM1 -> BatchNorm(inference)
// B=64, T=128, D=256, H=1024, 4H=4096, BT=8192 rows.
//
// Round-4 structure: NO separate GEMMs. Each timestep kernel computes
//   z = x_t @ W + h_{t-1} @ U + b   (W fused into the MFMA pass)
// Layer0: x_t = emb rows (K=256). Layer1: x_t = h0[t] (K=1024).
//
// All matrices stored FRAGMENT-MAJOR: 16B chunk (row-block rb, kc, lane ll)
// at ushort offset rb*(KCH*128) + kc*128 + ll*8  — a wave's MFMA operand
// load (lanes: ll=l&15, kc+=l>>4) is 1KB fully contiguous.
//
// Step grid: 256 WGs (4 wgM x 64 wgN, XCD-swizzled: bid[0:3)=wgN-hi) x 512
// thr (8 waves = 4 n-tiles x 2 k-halves), wave-local 4-chain MFMA, zbuf
// cross-wave reduce, epilogue owns (b,j): gates, c-update, BN, frag-major
// h writes assembled in LDS.  ~30us/step grid.sync measured r2 -> launches.
// ---------------------------------------------------------------------------

typedef __attribute__((ext_vector_type(8))) short short8;
typedef __attribute__((ext_vector_type(4))) float f32x4;
typedef unsigned short ushort_t;

__device__ __forceinline__ ushort_t f2b(float f) {
  __hip_bfloat16 h = __float2bfloat16(f);
  return *reinterpret_cast<ushort_t*>(&h);
}
__device__ __forceinline__ float fsigmoid(float x) {
  return 1.f / (1.f + __expf(-x));
}
__device__ __forceinline__ float ftanh(float x) {
  return 1.f - 2.f / (__expf(2.f * x) + 1.f);
}

// ---- convert W/U [K][4096col] f32 -> frag-major bf16 ----------------------
// thread <-> dst chunk (p, kc, pl); writes one 16B chunk (coalesced).
// kchlog = log2(K/8).
__global__ __launch_bounds__(256) void k_convert_frag(
    const float* __restrict__ src, ushort_t* __restrict__ dst, int kchlog) {
  int cid = blockIdx.x * 256 + threadIdx.x;
  int pl = cid & 15;
  int kc = (cid >> 4) & ((1 << kchlog) - 1);
  int p = cid >> (4 + kchlog);
  int pc = p * 16 + pl;
  int c = ((pc & 3) << 10) | (pc >> 2);     // original column
  short8 v;
#pragma unroll
  for (int e = 0; e < 8; ++e)
    v[e] = (short)f2b(src[(size_t)(kc * 8 + e) * 4096 + c]);
  *(short8*)(dst + (size_t)cid * 8) = v;
}

// ---- permute biases -------------------------------------------------------
__global__ __launch_bounds__(256) void k_bias(
    const float* __restrict__ b0, const float* __restrict__ b1,
    float* __restrict__ bp0, float* __restrict__ bp1) {
  int pc = blockIdx.x * 256 + threadIdx.x;
  int c = ((pc & 3) << 10) | (pc >> 2);
  bp0[pc] = b0[c];
  bp1[pc] = b1[c];
}

// ---- embedding gather -> frag-major Xef[t] (32KB per t) -------------------
__global__ __launch_bounds__(256) void k_gather(
    const int* __restrict__ tokens, const float* __restrict__ emb,
    ushort_t* __restrict__ Xef) {
  int row = blockIdx.x;            // row = t*64 + b
  int t = row >> 6, b = row & 63;
  int tok = tokens[b * 128 + t];
  int d = threadIdx.x;
  float v = emb[(size_t)tok * 256 + d];
  // chunk (rb=b>>4, kc=d>>3, ll=b&15), elem d&7
  Xef[(size_t)t * 16384 + (b >> 4) * 4096 + (d >> 3) * 128 + (b & 15) * 8 +
      (d & 7)] = f2b(v);
}

// ---- state init: h0 -> frag-major hfA; c0 -> c_st -------------------------
__global__ __launch_bounds__(256) void k_init(
    const float* __restrict__ h0, const float* __restrict__ c0,
    ushort_t* __restrict__ hfA, float* __restrict__ c_st) {
  int tid = blockIdx.x * 256 + threadIdx.x;
  int b = tid >> 10, j = tid & 1023;
  c_st[tid] = c0[tid];
  hfA[(b >> 4) * 16384 + (j >> 3) * 128 + (b & 15) * 8 + (j & 7)] =
      f2b(h0[tid]);
}

// ---- one fused LSTM timestep ----------------------------------------------
template <int LAYER>
__global__ __launch_bounds__(512, 2) void k_step(
    const ushort_t* __restrict__ hfin,   // frag h state (in)
    ushort_t* __restrict__ hfout,        // frag h state (out)
    const ushort_t* __restrict__ Uf,     // frag U (KCH=128)
    const ushort_t* __restrict__ Wf,     // frag W (L0 KCH=32, L1 KCH=128)
    const ushort_t* __restrict__ Xf,     // frag x_t (L0: Xef+t*16384, L1: H0f+t*65536)
    const float* __restrict__ bp,        // [4096] permuted bias
    float* __restrict__ c_st,            // [64][1024] f32
    ushort_t* __restrict__ H0f_out,      // L0: H0f + t*65536
    float* __restrict__ outp,            // L1: d_out
    const float* __restrict__ gamma, const float* __restrict__ beta,
    const float* __restrict__ mean, const float* __restrict__ var, int t) {
  const int tid = threadIdx.x;
  const int l = tid & 63;
  const int wv = tid >> 6;
  const int n = wv & 3;                 // n-tile (16 pc)
  const int kh = wv >> 2;               // k-half
  const int bid = blockIdx.x;
  const int wgN = ((bid & 7) << 3) | ((bid >> 3) & 7);  // XCD-stable slices
  const int wgM = bid >> 6;             // 0..3 (16 rows each)
  const int lg = l >> 4, ll = l & 15;
  const int p = wgN * 4 + n;            // 16-pc block index
  const int laneB = ll * 8;

  const ushort_t* Ub = Uf + p * 16384 + laneB;
  const ushort_t* Ab = hfin + wgM * 16384 + laneB;

  f32x4 acc[4] = {};
  if (kh == 0) {
    const int NK = (LAYER == 0) ? 20 : 32;   // U kc [0, NK*4)
#pragma unroll 4
    for (int k0 = 0; k0 < NK; ++k0) {
      int kc = k0 * 4 + lg;
      short8 a = *(const short8*)(Ab + kc * 128);
      short8 b = *(const short8*)(Ub + kc * 128);
      acc[k0 & 3] =
          __builtin_amdgcn_mfma_f32_16x16x32_bf16(a, b, acc[k0 & 3], 0, 0, 0);
    }
  } else {
    if (LAYER == 0) {
      // U kc 80..127 (12 steps)
#pragma unroll 4
      for (int k0 = 0; k0 < 12; ++k0) {
        int kc = 80 + k0 * 4 + lg;
        short8 a = *(const short8*)(Ab + kc * 128);
        short8 b = *(const short8*)(Ub + kc * 128);
        acc[k0 & 3] = __builtin_amdgcn_mfma_f32_16x16x32_bf16(a, b, acc[k0 & 3],
                                                              0, 0, 0);
      }
      // W0 part: K=256 (8 steps), A from Xf (KCH=32)
      const ushort_t* Xb = Xf + wgM * 4096 + laneB;
      const ushort_t* Wb = Wf + p * 4096 + laneB;
#pragma unroll 4
      for (int k0 = 0; k0 < 8; ++k0) {
        int kc = k0 * 4 + lg;
        short8 a = *(const short8*)(Xb + kc * 128);
        short8 b = *(const short8*)(Wb + kc * 128);
        acc[k0 & 3] = __builtin_amdgcn_mfma_f32_16x16x32_bf16(a, b, acc[k0 & 3],
                                                              0, 0, 0);
      }
    } else {
      // W1 part: K=1024 (32 steps), A = h0[t] frag (KCH=128)
      const ushort_t* Xb = Xf + wgM * 16384 + laneB;
      const ushort_t* Wb = Wf + p * 16384 + laneB;
#pragma unroll 4
      for (int k0 = 0; k0 < 32; ++k0) {
        int kc = k0 * 4 + lg;
        short8 a = *(const short8*)(Xb + kc * 128);
        short8 b = *(const short8*)(Wb + kc * 128);
        acc[k0 & 3] = __builtin_amdgcn_mfma_f32_16x16x32_bf16(a, b, acc[k0 & 3],
                                                              0, 0, 0);
      }
    }
  }

  __shared__ float zbuf[2][4][16][17];
  __shared__ float hbuf[16][17];
  {
    const int drow = lg * 4;
#pragma unroll
    for (int r = 0; r < 4; ++r)
      zbuf[kh][n][drow + r][ll] = acc[0][r] + acc[1][r] + acc[2][r] + acc[3][r];
  }
  __syncthreads();

  if (tid < 256) {
    const int b_loc = tid >> 4, j_loc = tid & 15;
    const int ne = j_loc >> 2;
    const int cb = (j_loc & 3) * 4;
    const int pcb = wgN * 64 + j_loc * 4;
    f32x4 bia = *(const f32x4*)(bp + pcb);

    float zi = zbuf[0][ne][b_loc][cb + 0] + zbuf[1][ne][b_loc][cb + 0] + bia[0];
    float zf = zbuf[0][ne][b_loc][cb + 1] + zbuf[1][ne][b_loc][cb + 1] + bia[1];
    float zg = zbuf[0][ne][b_loc][cb + 2] + zbuf[1][ne][b_loc][cb + 2] + bia[2];
    float zo = zbuf[0][ne][b_loc][cb + 3] + zbuf[1][ne][b_loc][cb + 3] + bia[3];

    const int b = wgM * 16 + b_loc;
    const int j = wgN * 16 + j_loc;
    const int idx = b * 1024 + j;
    float co = c_st[idx];
    float ii = fsigmoid(zi), ff = fsigmoid(zf), oo = fsigmoid(zo);
    float gg = ftanh(zg);
    float cn = ff * co + ii * gg;
    float hn = oo * ftanh(cn);

    c_st[idx] = cn;
    hbuf[b_loc][j_loc] = hn;
    if (LAYER == 1) {
      float inv = rsqrtf(var[j] + 1e-3f);
      float scl = inv * gamma[j];
      float sft = beta[j] - mean[j] * scl;
      outp[((size_t)b * 128 + t) * 1024 + j] = hn * scl + sft;
      if (t == 127) {
        outp[8388608 + idx] = hn;
        outp[8454144 + idx] = cn;
      }
    }
  }
  __syncthreads();

  // assemble frag-major h chunks (16B, coalesced)
  if (tid < 32) {
    const int row_lo = tid & 15, kcl = tid >> 4;   // kcl 0..1
    short8 v;
#pragma unroll
    for (int e = 0; e < 8; ++e)
      v[e] = (short)f2b(hbuf[row_lo][kcl * 8 + e]);
    const int uidx = wgM * 16384 + (wgN * 2 + kcl) * 128 + row_lo * 8;
    *(short8*)(hfout + uidx) = v;
    if (LAYER == 0) *(short8*)(H0f_out + uidx) = v;
  }
}

extern "C" void kernel_launch(void* const* d_in, const int* in_sizes, int n_in,
                              void* d_out, int out_size, void* d_ws,
                              size_t ws_size, hipStream_t stream) {
  const int* tokens = (const int*)d_in[0];
  const float* h0 = (const float*)d_in[1];
  const float* c0 = (const float*)d_in[2];
  const float* emb = (const float*)d_in[3];
  const float* W0 = (const float*)d_in[4];
  const float* U0 = (const float*)d_in[5];
  const float* b0 = (const float*)d_in[6];
  const float* W1 = (const float*)d_in[7];
  const float* U1 = (const float*)d_in[8];
  const float* b1 = (const float*)d_in[9];
  const float* gammap = (const float*)d_in[10];
  const float* betap = (const float*)d_in[11];
  const float* mmean = (const float*)d_in[12];
  const float* mvar = (const float*)d_in[13];

  char* ws = (char*)d_ws;
  ushort_t* Uf0 = (ushort_t*)(ws + 0);             //  8 MB frag U0
  ushort_t* Uf1 = (ushort_t*)(ws + 8388608);       //  8 MB frag U1
  ushort_t* Wf0 = (ushort_t*)(ws + 16777216);      //  2 MB frag W0 (K=256)
  ushort_t* Wf1 = (ushort_t*)(ws + 18874368);      //  8 MB frag W1
  float* bp0 = (float*)(ws + 27262976);            // 16 KB
  float* bp1 = (float*)(ws + 27279360);            // 16 KB
  ushort_t* Xef = (ushort_t*)(ws + 27295744);      //  4 MB frag emb rows
  ushort_t* H0f = (ushort_t*)(ws + 31490048);      // 16 MB frag h0 history
  ushort_t* hfA = (ushort_t*)(ws + 48267264);      // 128 KB frag h state
  ushort_t* hfB = (ushort_t*)(ws + 48398336);      // 128 KB
  float* c_st = (float*)(ws + 48529408);           // 256 KB

  k_convert_frag<<<2048, 256, 0, stream>>>(U0, Uf0, 7);
  k_convert_frag<<<2048, 256, 0, stream>>>(U1, Uf1, 7);
  k_convert_frag<<<512, 256, 0, stream>>>(W0, Wf0, 5);
  k_convert_frag<<<2048, 256, 0, stream>>>(W1, Wf1, 7);
  k_bias<<<16, 256, 0, stream>>>(b0, b1, bp0, bp1);
  k_gather<<<8192, 256, 0, stream>>>(tokens, emb, Xef);
  k_init<<<256, 256, 0, stream>>>(h0, c0, hfA, c_st);

  float* outp = (float*)d_out;

  // ---- layer 0: global step s = t ----
  for (int t = 0; t < 128; ++t) {
    const ushort_t* hin = (t & 1) ? hfB : hfA;
    ushort_t* hout = (t & 1) ? hfA : hfB;
    k_step<0><<<256, 512, 0, stream>>>(
        hin, hout, Uf0, Wf0, Xef + (size_t)t * 16384, bp0, c_st,
        H0f + (size_t)t * 65536, nullptr, nullptr, nullptr, nullptr, nullptr,
        t);
  }
  // ---- layer 1: global step s = 128 + t (parity continues; h/c carry) ----
  for (int t = 0; t < 128; ++t) {
    const ushort_t* hin = (t & 1) ? hfB : hfA;
    ushort_t* hout = (t & 1) ? hfA : hfB;
    k_step<1><<<256, 512, 0, stream>>>(
        hin, hout, Uf1, Wf1, H0f + (size_t)t * 65536, bp1, c_st, nullptr, outp,
        gammap, betap, mmean, mvar, t);
  }
}

// Round 6
// 1553.307 us; speedup vs baseline: 5.5344x; 1.0833x over previous
//
#include <hip/hip_runtime.h>
#include <hip/hip_bf16.h>

// ---------------------------------------------------------------------------
// Encoder: emb gather -> LSTM0 -> LSTM1 -> BatchNorm(inference)
// B=64, T=128, D=256, H=1024, 4H=4096, BT=8192 rows.
//
// Round-6 structure:
//  - XW = x@W precomputed by GEMMs; A operand of the GEMMs read directly from
//    fragment-major history buffers (16B chunk = 8 k-elems of one row).
//  - Recurrence: persistent kernels with PLAIN <<<128,256>>> launches
//    (1 WG/CU via 149KB LDS; 128 <= 256 CUs => co-resident by capacity; the
//    coop API silently failed in r5). U slice (64 pc x 1024 k) LDS-resident;
//    c in registers.
//  - h exchange: per-step-unique hall[t] slots (frag-major). Stores are
//    __hip_atomic_store(RELAXED, AGENT); loads are normal cached loads (no
//    slot line can be stale: first in-kernel touch is after its write;
//    cross-kernel coherence via dispatch boundaries proven in r1/r3/r4).
//  - Grid barrier: vmcnt(0) + relaxed agent atomicAdd + spin (no L2 wb/inv;
//    measured r2: cg::grid.sync() ~30us/step).
// ---------------------------------------------------------------------------

typedef __attribute__((ext_vector_type(8))) short short8;
typedef __attribute__((ext_vector_type(4))) short short4v;
typedef __attribute__((ext_vector_type(4))) float f32x4;
typedef __attribute__((ext_vector_type(16))) float f32x16;
typedef unsigned short ushort_t;

__device__ __forceinline__ void lgkm0_bar() {
  asm volatile("s_waitcnt lgkmcnt(0)" ::: "memory");
  __builtin_amdgcn_s_barrier();
}

__device__ __forceinline__ ushort_t f2b(float f) {
  __hip_bfloat16 h = __float2bfloat16(f);
  return *reinterpret_cast<ushort_t*>(&h);
}
__device__ __forceinline__ float b2f(ushort_t u) {
  unsigned int x = ((unsigned int)u) << 16;
  return __builtin_bit_cast(float, x);
}
__device__ __forceinline__ float fsigmoid(float x) {
  return 1.f / (1.f + __expf(-x));
}
__device__ __forceinline__ float ftanh(float x) {
  return 1.f - 2.f / (__expf(2.f * x) + 1.f);
}

__device__ __forceinline__ void gload_lds16(const ushort_t* g, ushort_t* l) {
  __builtin_amdgcn_global_load_lds(
      (const __attribute__((address_space(1))) unsigned int*)g,
      (__attribute__((address_space(3))) unsigned int*)l, 16, 0, 0);
}

// frag chunk offset (in ushorts) for row b, k-chunk kcg (8 elems), NKS = K/16
__device__ __forceinline__ size_t chunkoff(int b, int kcg, int NKS) {
  return (size_t)((((b >> 5) * NKS + (kcg >> 1)) << 6) |
                  ((b & 31) | ((kcg & 1) << 5))) * 8;
}

// ---- convert W [K][4096] f32 -> [pc][k] bf16 (GEMM B-operand) -------------
__global__ __launch_bounds__(256) void k_convert(
    const float* __restrict__ src, ushort_t* __restrict__ dst, int kshift) {
  size_t tid = (size_t)blockIdx.x * 256 + threadIdx.x;  // = k*4096 + c
  int k = (int)(tid >> 12);
  int c = (int)(tid & 4095);
  int pc = ((c & 1023) << 2) | (c >> 10);
  dst[((size_t)pc << kshift) + k] = f2b(src[tid]);
}

// ---- convert U [1024][4096] f32 -> per-WG frag slices ---------------------
// slice w (65536 us): ((nt*64 + ks)*64 + l)*8 + e:
//   pc = w*64 + nt*32 + (l&31), k = ks*16 + (l>>5)*8 + e
__global__ __launch_bounds__(256) void k_convert_ucoop(
    const float* __restrict__ src, ushort_t* __restrict__ dst) {
  int cid = blockIdx.x * 256 + threadIdx.x;
  int l = cid & 63;
  int ks = (cid >> 6) & 63;
  int nt = (cid >> 12) & 1;
  int w = cid >> 13;
  int pc = w * 64 + nt * 32 + (l & 31);
  int c = ((pc & 3) << 10) | (pc >> 2);
  int kb = ks * 16 + (l >> 5) * 8;
  short8 v;
#pragma unroll
  for (int e = 0; e < 8; ++e)
    v[e] = (short)f2b(src[(size_t)(kb + e) * 4096 + c]);
  *(short8*)(dst + (size_t)cid * 8) = v;
}

// ---- permute biases -------------------------------------------------------
__global__ __launch_bounds__(256) void k_bias(
    const float* __restrict__ b0, const float* __restrict__ b1,
    float* __restrict__ bp0, float* __restrict__ bp1) {
  int pc = blockIdx.x * 256 + threadIdx.x;
  int c = ((pc & 3) << 10) | (pc >> 2);
  bp0[pc] = b0[c];
  bp1[pc] = b1[c];
}

// ---- embedding gather -> frag-major Xef (32KB per t) ----------------------
__global__ __launch_bounds__(256) void k_gather(
    const int* __restrict__ tokens, const float* __restrict__ emb,
    ushort_t* __restrict__ Xef) {
  int row = blockIdx.x;            // row = t*64 + b
  int t = row >> 6, b = row & 63;
  int tok = tokens[b * 128 + t];
  int d = threadIdx.x;
  Xef[(size_t)t * 16384 + chunkoff(b, d >> 3, 16) + (d & 7)] =
      f2b(emb[(size_t)tok * 256 + d]);
}

// ---- state init: h0 -> hall[0] frag; c0 -> c_st; zero barriers ------------
__global__ __launch_bounds__(256) void k_init(
    const float* __restrict__ h0, const float* __restrict__ c0,
    ushort_t* __restrict__ hall, float* __restrict__ c_st,
    unsigned* __restrict__ bars) {
  int tid = blockIdx.x * 256 + threadIdx.x;
  int b = tid >> 10, jj = tid & 1023;
  c_st[tid] = c0[tid];
  hall[chunkoff(b, jj >> 3, 64) + (jj & 7)] = f2b(h0[tid]);
  if (tid < 2) bars[tid] = 0;
}

// ---- GEMM: C[8192][4096] = A[8192][K] * BT[4096][K]^T ---------------------
// A in frag layout (per-t stride NKS*1024 ushorts). 128x128 tile,
// global_load_lds staging, XCD-blocked mapping (8 wgM inner, wgN outer).
template <int NKS>
__global__ __launch_bounds__(256) void k_gemm(
    const ushort_t* __restrict__ Af, const ushort_t* __restrict__ BT,
    ushort_t* __restrict__ C) {
  const int K = NKS * 16;
  const int xcd = blockIdx.x & 7, loc = blockIdx.x >> 3;
  const int wgM = xcd * 8 + (loc & 7);
  const int wgN = loc >> 3;
  const int tid = threadIdx.x;
  const int l = tid & 63;
  const int wv = tid >> 6;
  const int wvM = wv & 1, wvN = wv >> 1;

  __shared__ __align__(16) ushort_t Alds[4096];
  __shared__ __align__(16) ushort_t Blds[4096];

  const int m0 = wgM * 128, n0 = wgN * 128;
  f32x4 acc[4][4] = {};

  for (int k0 = 0; k0 < K; k0 += 32) {
    __syncthreads();
#pragma unroll
    for (int jj = 0; jj < 2; ++jj) {
      int c = jj * 256 + tid;
      int kc = c >> 7, r = c & 127;
      int R = m0 + r, tt = R >> 6, b = R & 63;
      int kcg = (k0 >> 3) + kc;
      gload_lds16(Af + (size_t)tt * (NKS * 1024) + chunkoff(b, kcg, NKS),
                  (ushort_t*)&Alds[(size_t)(jj * 256 + (tid & ~63)) * 8]);
      gload_lds16(BT + (size_t)(n0 + r) * K + k0 + kc * 8,
                  (ushort_t*)&Blds[(size_t)(jj * 256 + (tid & ~63)) * 8]);
    }
    __syncthreads();

    short8 af[4], bf[4];
#pragma unroll
    for (int mt = 0; mt < 4; ++mt)
      af[mt] = *(const short8*)&Alds[((l >> 4) * 128 + wvM * 64 + mt * 16 + (l & 15)) * 8];
#pragma unroll
    for (int nt = 0; nt < 4; ++nt)
      bf[nt] = *(const short8*)&Blds[((l >> 4) * 128 + wvN * 64 + nt * 16 + (l & 15)) * 8];
#pragma unroll
    for (int mt = 0; mt < 4; ++mt)
#pragma unroll
      for (int nt = 0; nt < 4; ++nt)
        acc[mt][nt] =
            __builtin_amdgcn_mfma_f32_16x16x32_bf16(af[mt], bf[nt], acc[mt][nt], 0, 0, 0);
  }

  const int rr0 = wgM * 128 + wvM * 64 + (l >> 4) * 4;
  const int cc0 = wgN * 128 + wvN * 64 + (l & 15);
#pragma unroll
  for (int mt = 0; mt < 4; ++mt)
#pragma unroll
    for (int nt = 0; nt < 4; ++nt)
#pragma unroll
      for (int r = 0; r < 4; ++r)
        C[(size_t)(rr0 + mt * 16 + r) * 4096 + cc0 + nt * 16] =
            f2b(acc[mt][nt][r]);
}

// ---- persistent LSTM layer (128 steps), plain launch <<<128,256>>> --------
// WG (w = bid>>1, m = bid&1): rows m*32..+31, pc slice w (64 cols = 16 j).
// Waves (nt = wv&1, kh = wv>>1): 32x32x16 MFMA, K split by kh within phase.
template <int LAYER>
__global__ __launch_bounds__(256, 1) void k_pers(
    const ushort_t* __restrict__ Uf,    // frag slices, slice w at w*65536
    const ushort_t* __restrict__ XW,    // [8192][4096] bf16 row-major
    const float* __restrict__ bp,       // [4096] permuted bias
    ushort_t* __restrict__ hall,        // 129 slots x 65536 us (frag)
    float* __restrict__ c_st,           // [64][1024] f32
    float* __restrict__ outp,           // L1: d_out
    const float* __restrict__ gamma, const float* __restrict__ beta,
    const float* __restrict__ mean, const float* __restrict__ var,
    unsigned* __restrict__ bar) {
  const int bid = blockIdx.x;
  const int w = bid >> 1;               // pc-slice 0..63
  const int m = bid & 1;                // row half
  const int tid = threadIdx.x;
  const int l = tid & 63;
  const int wv = tid >> 6;
  const int nt = wv & 1, kh = wv >> 1;

  __shared__ __align__(16) ushort_t Ulds[2][64][512];  // 128KB [nt][ks][l*8]
  __shared__ __align__(16) char smem[16896];           // stage ∪ zls
  __shared__ ushort_t hbuf[32][16];
  ushort_t(*stage)[512] = (ushort_t(*)[512])smem;      // [16][512]
  float(*zls)[2][32][33] = (float(*)[2][32][33])smem;  // [kh][nt][row][col]

  // ---- stage U slice (128KB = 8192 chunks) ----
  {
    const ushort_t* src = Uf + (size_t)w * 65536;
    for (int i = tid; i < 8192; i += 256)
      *(short8*)((ushort_t*)Ulds + (size_t)i * 8) =
          *(const short8*)(src + (size_t)i * 8);
  }

  // ---- epilogue constants ----
  const int jl = tid & 15, bq = tid >> 4;   // bq 0..15
  const int j = w * 16 + jl;
  float creg[2];
#pragma unroll
  for (int q = 0; q < 2; ++q)
    creg[q] = c_st[(m * 32 + bq * 2 + q) * 1024 + j];
  const f32x4 bias_v = *(const f32x4*)(bp + w * 64 + jl * 4);
  float scl = 0.f, sft = 0.f;
  if (LAYER == 1) {
    float inv = rsqrtf(var[j] + 1e-3f);
    scl = inv * gamma[j];
    sft = beta[j] - mean[j] * scl;
  }
  lgkm0_bar();

  for (int t = 0; t < 128; ++t) {
    const ushort_t* hin =
        hall + (size_t)((LAYER == 1 && t == 0) ? 128 : t) * 65536;
    ushort_t* hout = hall + (size_t)(t + 1) * 65536;

    // prefetch XW for epilogue (2 x 8B, hidden under MFMA phases)
    short4v xw[2];
#pragma unroll
    for (int q = 0; q < 2; ++q)
      xw[q] = *(const short4v*)(
          XW + ((size_t)(t * 64 + m * 32 + bq * 2 + q) << 12) + w * 64 + jl * 4);

    // issue all h loads (16 chunks/thread; compiler pipelines the waits)
    short8 hr[4][4];
#pragma unroll
    for (int ph = 0; ph < 4; ++ph)
#pragma unroll
      for (int i = 0; i < 4; ++i) {
        int ks = ph * 16 + wv * 4 + i;
        hr[ph][i] = *(const short8*)(hin + (size_t)((m * 64 + ks) * 64 + l) * 8);
      }

    f32x16 acc[4] = {};
#pragma unroll
    for (int ph = 0; ph < 4; ++ph) {
      lgkm0_bar();   // stage (or zls from prev step) free
#pragma unroll
      for (int i = 0; i < 4; ++i)
        *(short8*)&stage[wv * 4 + i][l * 8] = hr[ph][i];
      lgkm0_bar();   // stage visible
#pragma unroll
      for (int i2 = 0; i2 < 8; ++i2) {
        int ksl = kh * 8 + i2;
        short8 a = *(const short8*)&stage[ksl][l * 8];
        short8 b = *(const short8*)&Ulds[nt][ph * 16 + ksl][l * 8];
        acc[i2 & 3] =
            __builtin_amdgcn_mfma_f32_32x32x16_bf16(a, b, acc[i2 & 3], 0, 0, 0);
      }
    }
    lgkm0_bar();     // all stage reads done before zls overwrite

    // z partials to LDS (32x32 C layout: col=l&31, row=(r&3)+8*(r>>2)+4*(l>>5))
    f32x16 zt = acc[0] + acc[1] + acc[2] + acc[3];
#pragma unroll
    for (int r = 0; r < 16; ++r) {
      int row = (r & 3) + 8 * (r >> 2) + 4 * (l >> 5);
      zls[kh][nt][row][l & 31] = zt[r];
    }
    lgkm0_bar();

    // ---- epilogue: gates, c-update, BN, h ----
#pragma unroll
    for (int q = 0; q < 2; ++q) {
      const int b_loc = bq * 2 + q;
      const int nte = jl >> 3;
      const int cb = (jl & 7) * 4;
      float zi = zls[0][nte][b_loc][cb + 0] + zls[1][nte][b_loc][cb + 0] +
                 b2f((ushort_t)xw[q][0]) + bias_v[0];
      float zf = zls[0][nte][b_loc][cb + 1] + zls[1][nte][b_loc][cb + 1] +
                 b2f((ushort_t)xw[q][1]) + bias_v[1];
      float zg = zls[0][nte][b_loc][cb + 2] + zls[1][nte][b_loc][cb + 2] +
                 b2f((ushort_t)xw[q][2]) + bias_v[2];
      float zo = zls[0][nte][b_loc][cb + 3] + zls[1][nte][b_loc][cb + 3] +
                 b2f((ushort_t)xw[q][3]) + bias_v[3];
      float ii = fsigmoid(zi), ff = fsigmoid(zf), oo = fsigmoid(zo);
      float gg = ftanh(zg);
      creg[q] = ff * creg[q] + ii * gg;
      float hn = oo * ftanh(creg[q]);
      hbuf[b_loc][jl] = f2b(hn);
      const int b = m * 32 + b_loc;
      if (LAYER == 1) {
        outp[((size_t)b * 128 + t) * 1024 + j] = hn * scl + sft;
        if (t == 127) {
          outp[8388608 + b * 1024 + j] = hn;
          outp[8454144 + b * 1024 + j] = creg[q];
        }
      } else {
        if (t == 127) c_st[b * 1024 + j] = creg[q];
      }
    }
    lgkm0_bar();     // hbuf ready

    // ---- assemble h chunks; agent-scope stores (cross-XCD visible) ----
    if (tid < 64) {
      short8 v = *(const short8*)&hbuf[l & 31][(l >> 5) * 8];
      union { short8 s; unsigned u[4]; } cv;
      cv.s = v;
      unsigned* dst = (unsigned*)(hout + (size_t)((m * 64 + w) * 64 + l) * 8);
#pragma unroll
      for (int wi = 0; wi < 4; ++wi)
        __hip_atomic_store(dst + wi, cv.u[wi], __ATOMIC_RELAXED,
                           __HIP_MEMORY_SCOPE_AGENT);
    }

    // ---- grid barrier: drain stores, arrive, spin ----
    asm volatile("s_waitcnt vmcnt(0)" ::: "memory");
    __builtin_amdgcn_s_barrier();
    if (tid == 0) {
      __hip_atomic_fetch_add(bar, 1u, __ATOMIC_RELAXED,
                             __HIP_MEMORY_SCOPE_AGENT);
      unsigned tg = 128u * (unsigned)(t + 1);
      while (__hip_atomic_load(bar, __ATOMIC_RELAXED,
                               __HIP_MEMORY_SCOPE_AGENT) < tg)
        __builtin_amdgcn_s_sleep(8);
    }
    __builtin_amdgcn_s_barrier();
  }
}

extern "C" void kernel_launch(void* const* d_in, const int* in_sizes, int n_in,
                              void* d_out, int out_size, void* d_ws,
                              size_t ws_size, hipStream_t stream) {
  const int* tokens = (const int*)d_in[0];
  const float* h0 = (const float*)d_in[1];
  const float* c0 = (const float*)d_in[2];
  const float* emb = (const float*)d_in[3];
  const float* W0 = (const float*)d_in[4];
  const float* U0 = (const float*)d_in[5];
  const float* b0 = (const float*)d_in[6];
  const float* W1 = (const float*)d_in[7];
  const float* U1 = (const float*)d_in[8];
  const float* b1 = (const float*)d_in[9];
  const float* gammap = (const float*)d_in[10];
  const float* betap = (const float*)d_in[11];
  const float* mmean = (const float*)d_in[12];
  const float* mvar = (const float*)d_in[13];

  char* ws = (char*)d_ws;
  ushort_t* Uc0 = (ushort_t*)(ws + 0);             //  8 MB frag U0
  ushort_t* Uc1 = (ushort_t*)(ws + 8388608);       //  8 MB frag U1
  ushort_t* W0f = (ushort_t*)(ws + 16777216);      //  2 MB [pc][256]
  ushort_t* W1f = (ushort_t*)(ws + 18874368);      //  8 MB [pc][1024]
  float* bp0 = (float*)(ws + 27262976);            // 16 KB
  float* bp1 = (float*)(ws + 27279360);            // 16 KB
  ushort_t* Xef = (ushort_t*)(ws + 27295744);      //  4 MB frag emb
  ushort_t* XW = (ushort_t*)(ws + 31490048);       // 64 MB [8192][4096]
  ushort_t* hall = (ushort_t*)(ws + 98598912);     // 16.5 MB: 129 x 128KB
  float* c_st = (float*)(ws + 115507200);          // 256 KB
  unsigned* bars = (unsigned*)(ws + 115769344);    // 8 B

  k_convert_ucoop<<<2048, 256, 0, stream>>>(U0, Uc0);
  k_convert_ucoop<<<2048, 256, 0, stream>>>(U1, Uc1);
  k_convert<<<4096, 256, 0, stream>>>(W0, W0f, 8);
  k_convert<<<16384, 256, 0, stream>>>(W1, W1f, 10);
  k_bias<<<16, 256, 0, stream>>>(b0, b1, bp0, bp1);
  k_gather<<<8192, 256, 0, stream>>>(tokens, emb, Xef);
  k_init<<<256, 256, 0, stream>>>(h0, c0, hall, c_st, bars);

  float* outp = (float*)d_out;

  // ---- layer 0 ----
  k_gemm<16><<<2048, 256, 0, stream>>>(Xef, W0f, XW);
  k_pers<0><<<128, 256, 0, stream>>>(Uc0, XW, bp0, hall, c_st, nullptr,
                                     nullptr, nullptr, nullptr, nullptr,
                                     bars + 0);

  // ---- layer 1 (A of GEMM = hall slots 1..128 = L0 outputs) ----
  k_gemm<64><<<2048, 256, 0, stream>>>(hall + 65536, W1f, XW);
  k_pers<1><<<128, 256, 0, stream>>>(Uc1, XW, bp1, hall, c_st, outp, gammap,
                                     betap, mmean, mvar, bars + 1);
}